// Round 1
// baseline (240.476 us; speedup 1.0000x reference)
//
#include <hip/hip_runtime.h>

#define BATCH 4
#define CHAN 128
#define HGT 96
#define WID 160
#define TILE_Y 16
#define TILE_X 32
#define CC 8
#define NCHUNK (CHAN / CC)
#define THREADS 128

// Output channel index for displacement (dy,dx), matching _displacements(4) order.
__device__ __forceinline__ int chan_of(int dy, int dx) {
    if (dy == 0 && dx == 0) return 0;
    if (dx == 0) { int i = dy < 0 ? -dy : dy; return 1 + (i - 1) * 20 + (dy < 0 ? 0 : 1); }
    if (dy == 0) { int i = dx < 0 ? -dx : dx; return 1 + (i - 1) * 20 + (dx < 0 ? 2 : 3); }
    int i = dy < 0 ? -dy : dy;
    int j = dx < 0 ? -dx : dx;
    int s = (dy < 0) ? (dx < 0 ? 0 : 2) : (dx < 0 ? 3 : 1);
    return 1 + (i - 1) * 20 + 4 + (j - 1) * 4 + s;
}

__global__ __launch_bounds__(THREADS, 2)
void cost_volume_kernel(const float* __restrict__ src,
                        const float* __restrict__ tgt,
                        float* __restrict__ out) {
    // tgt tile: 18 rows (16 + dy spread of 2) x 40 cols (32 + 8 halo), padded to 44
    // src tile: 16 x 32, padded to 36
    __shared__ __align__(16) float s_tgt[CC][TILE_Y + 2][TILE_X + 12];
    __shared__ __align__(16) float s_src[CC][TILE_Y][TILE_X + 4];

    const int tid = threadIdx.x;
    const int tx  = tid & 7;    // 0..7, 4 pixels each along x
    const int ty  = tid >> 3;   // 0..15
    const int x0  = blockIdx.x * TILE_X;
    const int y0  = blockIdx.y * TILE_Y;
    const int b   = blockIdx.z / 3;
    const int g   = blockIdx.z % 3;      // dy group
    const int dy0 = 3 * g - 4;           // group dys: dy0, dy0+1, dy0+2
    const int px0 = tx * 4;

    float acc[27][4];
    #pragma unroll
    for (int i = 0; i < 27; ++i)
        #pragma unroll
        for (int p = 0; p < 4; ++p) acc[i][p] = 0.f;

    #pragma unroll 1
    for (int ch = 0; ch < NCHUNK; ++ch) {
        const int c0 = ch * CC;
        __syncthreads();
        // --- stage tgt: CC x 18 rows x 10 float4 (cols 0..39), zero-fill OOB halo.
        // gx is 4-aligned and W%4==0, so each float4 is entirely in or out.
        for (int u = tid; u < CC * 18 * 10; u += THREADS) {
            int c   = u / 180;
            int rem = u - c * 180;
            int r   = rem / 10;
            int q   = rem - r * 10;
            int gy  = y0 + dy0 + r;
            int gx  = x0 - 4 + q * 4;
            float4 v = make_float4(0.f, 0.f, 0.f, 0.f);
            if ((unsigned)gy < (unsigned)HGT && (unsigned)gx < (unsigned)WID) {
                v = *reinterpret_cast<const float4*>(
                        tgt + (((b * CHAN + c0 + c) * HGT + gy) * WID + gx));
            }
            *reinterpret_cast<float4*>(&s_tgt[c][r][q * 4]) = v;
        }
        // --- stage src: CC x 16 rows x 8 float4, always in bounds.
        for (int u = tid; u < CC * 16 * 8; u += THREADS) {
            int c   = u >> 7;
            int rem = u & 127;
            int r   = rem >> 3;
            int q   = rem & 7;
            float4 v = *reinterpret_cast<const float4*>(
                    src + (((b * CHAN + c0 + c) * HGT + (y0 + r)) * WID + (x0 + q * 4)));
            *reinterpret_cast<float4*>(&s_src[c][r][q * 4]) = v;
        }
        __syncthreads();

        // --- compute: per channel, 1 src b128 + 9 tgt b128 feed 108 FMAs
        #pragma unroll
        for (int c = 0; c < CC; ++c) {
            float4 sv4 = *reinterpret_cast<const float4*>(&s_src[c][ty][px0]);
            float sv[4] = {sv4.x, sv4.y, sv4.z, sv4.w};
            #pragma unroll
            for (int dyi = 0; dyi < 3; ++dyi) {
                const float* row = &s_tgt[c][ty + dyi][px0];
                float4 w0 = *reinterpret_cast<const float4*>(row);
                float4 w1 = *reinterpret_cast<const float4*>(row + 4);
                float4 w2 = *reinterpret_cast<const float4*>(row + 8);
                float w[12] = {w0.x, w0.y, w0.z, w0.w,
                               w1.x, w1.y, w1.z, w1.w,
                               w2.x, w2.y, w2.z, w2.w};
                #pragma unroll
                for (int dx4 = 0; dx4 < 9; ++dx4) {
                    #pragma unroll
                    for (int p = 0; p < 4; ++p)
                        acc[dyi * 9 + dx4][p] += sv[p] * w[dx4 + p];
                }
            }
        }
    }

    // --- epilogue: each thread writes 27 float4s (channels disjoint across dy groups)
    const float inv = 1.0f / 81.0f;
    const int gy  = y0 + ty;
    const int gxb = x0 + px0;
    #pragma unroll
    for (int dyi = 0; dyi < 3; ++dyi) {
        int dy = dy0 + dyi;
        #pragma unroll
        for (int dx4 = 0; dx4 < 9; ++dx4) {
            int d = chan_of(dy, dx4 - 4);
            float4 o = make_float4(acc[dyi * 9 + dx4][0] * inv,
                                   acc[dyi * 9 + dx4][1] * inv,
                                   acc[dyi * 9 + dx4][2] * inv,
                                   acc[dyi * 9 + dx4][3] * inv);
            *reinterpret_cast<float4*>(
                out + (((b * 81 + d) * HGT + gy) * WID + gxb)) = o;
        }
    }
}

extern "C" void kernel_launch(void* const* d_in, const int* in_sizes, int n_in,
                              void* d_out, int out_size, void* d_ws, size_t ws_size,
                              hipStream_t stream) {
    const float* src = (const float*)d_in[0];
    const float* tgt = (const float*)d_in[1];
    float* out = (float*)d_out;
    dim3 grid(WID / TILE_X, HGT / TILE_Y, BATCH * 3);  // 5 x 6 x 12 = 360 blocks
    cost_volume_kernel<<<grid, dim3(THREADS, 1, 1), 0, stream>>>(src, tgt, out);
}